// Round 1
// baseline (208.133 us; speedup 1.0000x reference)
//
#include <hip/hip_runtime.h>
#include <stdint.h>

// Problem constants (fixed by the reference setup):
//   logits (2,4,128,128,128) fp32, target one-hot same shape.
#define NVOX (1u << 21)            // 128^3 voxels per batch (exactly 2^21)
#define NB   2                     // batches
#define KSEL 419430u               // int(0.2 * 2^21)
#define TPB  256
#define VPB  4096                  // voxels per block in pass kernels
#define BPB  ((int)(NVOX / VPB))   // 512 blocks per batch
#define NBLK (NB * BPB)            // 1024 blocks
#define NCOPY 64                   // accumulator spreading to kill atomic contention

__device__ __forceinline__ float wred64(float v) {
#pragma unroll
  for (int o = 32; o > 0; o >>= 1) v += __shfl_down(v, o, 64);
  return v;
}

// Pass 1: compute CE per voxel (store to ws), dice partial sums, and the
// level-1 radix histogram (top 11 bits of the nonnegative CE float).
__global__ __launch_bounds__(TPB) void k1_ce_dice_hist(
    const float* __restrict__ logits, const float* __restrict__ target,
    float* __restrict__ ce, uint32_t* __restrict__ hist1,
    float* __restrict__ dice_acc /* [NCOPY][NB][12]: sp[4], num[4], cnt[4] */)
{
  __shared__ uint32_t sh[2048];
  const int tid = threadIdx.x;
  for (int i = tid; i < 2048; i += TPB) sh[i] = 0;
  __syncthreads();

  const int blk = blockIdx.x;
  const int b = blk / BPB;
  const size_t v0 = (size_t)(blk % BPB) * VPB;
  const float* lg = logits + (size_t)b * 4 * NVOX + v0;
  const float* tg = target + (size_t)b * 4 * NVOX + v0;
  float* ceb = ce + ((size_t)b << 21) + v0;

  float sp[4] = {0.f,0.f,0.f,0.f}, nm[4] = {0.f,0.f,0.f,0.f}, ct[4] = {0.f,0.f,0.f,0.f};

  for (int i = tid * 4; i < VPB; i += TPB * 4) {
    float4 L[4], T[4];
#pragma unroll
    for (int c = 0; c < 4; ++c) {
      L[c] = *(const float4*)(lg + (size_t)c * NVOX + i);
      T[c] = *(const float4*)(tg + (size_t)c * NVOX + i);
    }
    float4 CE;
    float* cep = (float*)&CE;
#pragma unroll
    for (int j = 0; j < 4; ++j) {
      float l[4], t[4];
#pragma unroll
      for (int c = 0; c < 4; ++c) {
        l[c] = ((const float*)&L[c])[j];
        t[c] = ((const float*)&T[c])[j];
      }
      float m = fmaxf(fmaxf(l[0], l[1]), fmaxf(l[2], l[3]));
      float e[4]; float s = 0.f;
#pragma unroll
      for (int c = 0; c < 4; ++c) { e[c] = __expf(l[c] - m); s += e[c]; }
      float inv = 1.f / s;
      float lse = __logf(s);                       // s >= 1 -> lse >= 0
      float ly = l[0]*t[0] + l[1]*t[1] + l[2]*t[2] + l[3]*t[3]; // exact: t is one-hot
      float cev = (m - ly) + lse;                  // >= 0 => uint bits order-monotonic
      cep[j] = cev;
      atomicAdd(&sh[__float_as_uint(cev) >> 21], 1u);
#pragma unroll
      for (int c = 0; c < 4; ++c) {
        float p = e[c] * inv;
        sp[c] += p;
        nm[c] += p * t[c];
        ct[c] += t[c];
      }
    }
    *(float4*)(ceb + i) = CE;
  }

  // dice: wave-reduce then one atomic set per wave into a spread copy
#pragma unroll
  for (int c = 0; c < 4; ++c) { sp[c] = wred64(sp[c]); nm[c] = wred64(nm[c]); ct[c] = wred64(ct[c]); }
  if ((tid & 63) == 0) {
    float* dst = dice_acc + ((size_t)(blk & (NCOPY - 1)) * NB + b) * 12;
#pragma unroll
    for (int c = 0; c < 4; ++c) {
      atomicAdd(dst + c,     sp[c]);
      atomicAdd(dst + 4 + c, nm[c]);
      atomicAdd(dst + 8 + c, ct[c]);
    }
  }
  __syncthreads();
  for (int i = tid; i < 2048; i += TPB) {
    uint32_t cv = sh[i];
    if (cv) atomicAdd(&hist1[b * 2048 + i], cv);
  }
}

// Radix refinement pass over stored CE.
// pass==2: sum values with top11 > b1; histogram mid-11-bits of top11 == b1.
// pass==3: within top11==b1: sum values with mid11 > b2; histogram low-10-bits of mid11 == b2.
__global__ __launch_bounds__(TPB) void k_pass(
    const float* __restrict__ ce,
    const uint32_t* __restrict__ b1p, const uint32_t* __restrict__ b2p,
    uint32_t* __restrict__ hist_out, float* __restrict__ sum_above, int pass)
{
  __shared__ uint32_t sh[2048];
  __shared__ float wsum[TPB / 64];
  const int nb = (pass == 2) ? 2048 : 1024;
  const int tid = threadIdx.x;
  for (int i = tid; i < nb; i += TPB) sh[i] = 0;
  __syncthreads();

  const int blk = blockIdx.x;
  const int b = blk / BPB;
  const size_t v0 = (size_t)(blk % BPB) * VPB;
  const float* cb = ce + ((size_t)b << 21) + v0;
  const uint32_t b1 = b1p[b];
  const uint32_t b2 = (pass == 3) ? b2p[b] : 0u;
  float local = 0.f;

  for (int i = tid * 4; i < VPB; i += TPB * 4) {
    float4 V = *(const float4*)(cb + i);
    const float* vp = (const float*)&V;
#pragma unroll
    for (int j = 0; j < 4; ++j) {
      uint32_t bits = __float_as_uint(vp[j]);
      uint32_t t11 = bits >> 21;
      if (pass == 2) {
        if (t11 > b1) local += vp[j];
        else if (t11 == b1) atomicAdd(&sh[(bits >> 10) & 2047u], 1u);
      } else {
        if (t11 == b1) {
          uint32_t m11 = (bits >> 10) & 2047u;
          if (m11 > b2) local += vp[j];
          else if (m11 == b2) atomicAdd(&sh[bits & 1023u], 1u);
        }
      }
    }
  }

  local = wred64(local);
  if ((tid & 63) == 0) wsum[tid >> 6] = local;
  __syncthreads();
  if (tid == 0) {
    float t = 0.f;
#pragma unroll
    for (int w = 0; w < TPB / 64; ++w) t += wsum[w];
    if (t != 0.f) atomicAdd(&sum_above[b * NCOPY + (blk & (NCOPY - 1))], t);
  }
  for (int i = tid; i < nb; i += TPB) {
    uint32_t cv = sh[i];
    if (cv) atomicAdd(&hist_out[(size_t)b * nb + i], cv);
  }
}

// Scan a histogram from the top to find the bucket containing the k-th
// largest element. One block per batch. final_mode: reconstruct the exact
// float value of the last bucket (all 32 bits known) and emit topk_sum.
__global__ __launch_bounds__(256) void k_scan(
    const uint32_t* __restrict__ hist, int nb,
    const uint32_t* __restrict__ k_ptr, uint32_t k_imm,
    uint32_t* __restrict__ out_b, uint32_t* __restrict__ out_rem,
    int final_mode,
    const uint32_t* __restrict__ b1p, const uint32_t* __restrict__ b2p,
    const float* __restrict__ sum_above, float* __restrict__ topk_sum)
{
  const int b = blockIdx.x;
  const int tid = threadIdx.x;
  __shared__ uint32_t chunk[256];
  const int per = nb >> 8;
  const uint32_t* h = hist + (size_t)b * nb;
  uint32_t s = 0;
  for (int j = 0; j < per; ++j) s += h[tid * per + j];
  chunk[tid] = s;
  __syncthreads();
  if (tid == 0) {
    uint32_t k = k_ptr ? k_ptr[b] : k_imm;
    uint32_t cum = 0;
    int ci = 255;
    for (; ci > 0; --ci) {
      uint32_t c = chunk[ci];
      if (cum + c >= k) break;
      cum += c;
    }
    int bkt = ci * per;
    for (int j = per - 1; j >= 0; --j) {
      uint32_t c = h[ci * per + j];
      if (cum + c >= k) { bkt = ci * per + j; break; }
      cum += c;
    }
    out_b[b] = (uint32_t)bkt;
    uint32_t rem = k - cum;   // 1 <= rem <= hist[bkt]
    out_rem[b] = rem;
    if (final_mode) {
      float sa = 0.f;
      for (int r = 0; r < NCOPY; ++r) sa += sum_above[b * NCOPY + r];
      uint32_t bits = (b1p[b] << 21) | (b2p[b] << 10) | (uint32_t)bkt;
      topk_sum[b] = sa + (float)rem * __uint_as_float(bits);
    }
  }
}

__global__ __launch_bounds__(64) void k_final(
    const float* __restrict__ topk_sum,
    const float* __restrict__ dice_acc, float* __restrict__ out)
{
  const int r = threadIdx.x;  // one lane per spread copy
  float acc[24];
#pragma unroll
  for (int i = 0; i < 24; ++i) acc[i] = wred64(dice_acc[(size_t)r * 24 + i]);
  if (r == 0) {
    float dl = 0.f;
#pragma unroll
    for (int b = 0; b < 2; ++b)
#pragma unroll
      for (int c = 1; c < 4; ++c) {
        float sp = acc[b * 12 + c];
        float nm = acc[b * 12 + 4 + c];
        float ct = acc[b * 12 + 8 + c];
        dl += 1.f - (2.f * nm) / (sp + ct + 1e-6f);
      }
    float topk = 0.5f * (topk_sum[0] + topk_sum[1]) / (float)KSEL;
    out[0] = topk + 0.5f * (dl / 6.f);
  }
}

extern "C" void kernel_launch(void* const* d_in, const int* in_sizes, int n_in,
                              void* d_out, int out_size, void* d_ws, size_t ws_size,
                              hipStream_t stream) {
  (void)in_sizes; (void)n_in; (void)out_size; (void)ws_size;
  const float* logits = (const float*)d_in[0];
  const float* target = (const float*)d_in[1];
  float* out = (float*)d_out;

  // Workspace layout: [ce: NB*NVOX floats][hist/scan/dice accumulators]
  char* ws = (char*)d_ws;
  float* ce = (float*)ws;
  const size_t CE_BYTES = (size_t)NB * NVOX * sizeof(float);   // 16 MiB
  uint32_t* small = (uint32_t*)(ws + CE_BYTES);
  uint32_t* hist1 = small;                 // NB*2048
  uint32_t* hist2 = hist1 + NB * 2048;     // NB*2048
  uint32_t* hist3 = hist2 + NB * 2048;     // NB*1024
  uint32_t* b1   = hist3 + NB * 1024;
  uint32_t* b2   = b1 + NB;
  uint32_t* b3   = b2 + NB;
  uint32_t* rem1 = b3 + NB;
  uint32_t* rem2 = rem1 + NB;
  uint32_t* rem3 = rem2 + NB;
  float* sum_above = (float*)(rem3 + NB);  // NB*NCOPY
  float* topk_sum  = sum_above + NB * NCOPY;
  float* dice_acc  = topk_sum + NB;        // NCOPY*NB*12
  const size_t SMALL_BYTES =
      (size_t)((char*)(dice_acc + (size_t)NCOPY * NB * 12) - (char*)small);

  // ws is re-poisoned to 0xAA before every launch: zero all accumulators.
  hipMemsetAsync(small, 0, SMALL_BYTES, stream);

  k1_ce_dice_hist<<<NBLK, TPB, 0, stream>>>(logits, target, ce, hist1, dice_acc);
  k_scan<<<NB, 256, 0, stream>>>(hist1, 2048, nullptr, KSEL, b1, rem1, 0,
                                 nullptr, nullptr, nullptr, nullptr);
  k_pass<<<NBLK, TPB, 0, stream>>>(ce, b1, b2, hist2, sum_above, 2);
  k_scan<<<NB, 256, 0, stream>>>(hist2, 2048, rem1, 0u, b2, rem2, 0,
                                 nullptr, nullptr, nullptr, nullptr);
  k_pass<<<NBLK, TPB, 0, stream>>>(ce, b1, b2, hist3, sum_above, 3);
  k_scan<<<NB, 256, 0, stream>>>(hist3, 1024, rem2, 0u, b3, rem3, 1,
                                 b1, b2, sum_above, topk_sum);
  k_final<<<1, 64, 0, stream>>>(topk_sum, dice_acc, out);
}

// Round 3
// 204.707 us; speedup vs baseline: 1.0167x; 1.0167x over previous
//
#include <hip/hip_runtime.h>
#include <stdint.h>

// Problem constants (fixed by the reference setup):
//   logits (2,4,128,128,128) fp32, target one-hot same shape.
#define NVOX (1u << 21)            // 128^3 voxels per batch (exactly 2^21)
#define NB   2                     // batches
#define KSEL 419430u               // int(0.2 * 2^21)
#define TPB  256
#define VPB  2048                  // voxels per block  -> 8 blocks/CU (full wave cap)
#define BPB  ((int)(NVOX / VPB))   // 1024 blocks per batch
#define NBLK (NB * BPB)            // 2048 blocks
#define NCOPY 64                   // accumulator spreading to kill atomic contention
#define NBIN 4096                  // 12-bit radix buckets at both levels
#define L1SH 19                    // level-1 bucket = bits[30:19] (CE >= 0 so bit31=0)

__device__ __forceinline__ float wred64(float v) {
#pragma unroll
  for (int o = 32; o > 0; o >>= 1) v += __shfl_down(v, o, 64);
  return v;
}

// Pass 1: compute CE per voxel (store to ws), dice partial sums, and the
// level-1 radix histogram (bits[30:19] of the nonnegative CE float).
__global__ __launch_bounds__(TPB, 8) void k1_ce_dice_hist(
    const float* __restrict__ logits, const float* __restrict__ target,
    float* __restrict__ ce, uint32_t* __restrict__ hist1,
    float* __restrict__ dice_acc /* [NCOPY][NB][12]: sp[4], num[4], cnt[4] */)
{
  __shared__ uint32_t sh[NBIN];
  const int tid = threadIdx.x;
  for (int i = tid; i < NBIN; i += TPB) sh[i] = 0;
  __syncthreads();

  const int blk = blockIdx.x;
  const int b = blk / BPB;
  const size_t v0 = (size_t)(blk % BPB) * VPB;
  const float* lg = logits + (size_t)b * 4 * NVOX + v0;
  const float* tg = target + (size_t)b * 4 * NVOX + v0;
  float* ceb = ce + ((size_t)b << 21) + v0;

  float sp[4] = {0.f,0.f,0.f,0.f}, nm[4] = {0.f,0.f,0.f,0.f}, ct[4] = {0.f,0.f,0.f,0.f};

#pragma unroll 2
  for (int i = tid * 4; i < VPB; i += TPB * 4) {
    float4 L[4], T[4];
#pragma unroll
    for (int c = 0; c < 4; ++c) {
      L[c] = *(const float4*)(lg + (size_t)c * NVOX + i);
      T[c] = *(const float4*)(tg + (size_t)c * NVOX + i);
    }
    float4 CE;
    float* cep = (float*)&CE;
#pragma unroll
    for (int j = 0; j < 4; ++j) {
      float l[4], t[4];
#pragma unroll
      for (int c = 0; c < 4; ++c) {
        l[c] = ((const float*)&L[c])[j];
        t[c] = ((const float*)&T[c])[j];
      }
      float m = fmaxf(fmaxf(l[0], l[1]), fmaxf(l[2], l[3]));
      float e[4]; float s = 0.f;
#pragma unroll
      for (int c = 0; c < 4; ++c) { e[c] = __expf(l[c] - m); s += e[c]; }
      float inv = 1.f / s;
      float lse = __logf(s);                       // s >= 1 -> lse >= 0
      float ly = l[0]*t[0] + l[1]*t[1] + l[2]*t[2] + l[3]*t[3]; // exact: t one-hot
      float cev = (m - ly) + lse;                  // >= 0 => uint bits order-monotonic
      cep[j] = cev;
      atomicAdd(&sh[__float_as_uint(cev) >> L1SH], 1u);
#pragma unroll
      for (int c = 0; c < 4; ++c) {
        float p = e[c] * inv;
        sp[c] += p;
        nm[c] += p * t[c];
        ct[c] += t[c];
      }
    }
    *(float4*)(ceb + i) = CE;
  }

  // dice: wave-reduce then one atomic per component per wave into a spread copy
#pragma unroll
  for (int c = 0; c < 4; ++c) { sp[c] = wred64(sp[c]); nm[c] = wred64(nm[c]); ct[c] = wred64(ct[c]); }
  if ((tid & 63) == 0) {
    float* dst = dice_acc + ((size_t)(blk & (NCOPY - 1)) * NB + b) * 12;
#pragma unroll
    for (int c = 0; c < 4; ++c) {
      atomicAdd(dst + c,     sp[c]);
      atomicAdd(dst + 4 + c, nm[c]);
      atomicAdd(dst + 8 + c, ct[c]);
    }
  }
  __syncthreads();
  for (int i = tid; i < NBIN; i += TPB) {
    uint32_t cv = sh[i];
    if (cv) atomicAdd(&hist1[b * NBIN + i], cv);
  }
}

// Level-2 refinement over stored CE: sum values strictly above the level-1
// tie bucket; histogram bits[18:7] within the tie bucket.
__global__ __launch_bounds__(TPB, 8) void k_pass2(
    const float* __restrict__ ce, const uint32_t* __restrict__ b1p,
    uint32_t* __restrict__ hist2, float* __restrict__ sum_above)
{
  __shared__ uint32_t sh[NBIN];
  __shared__ float wsum[TPB / 64];
  const int tid = threadIdx.x;
  for (int i = tid; i < NBIN; i += TPB) sh[i] = 0;
  __syncthreads();

  const int blk = blockIdx.x;
  const int b = blk / BPB;
  const size_t v0 = (size_t)(blk % BPB) * VPB;
  const float* cb = ce + ((size_t)b << 21) + v0;
  const uint32_t b1 = b1p[b];
  float local = 0.f;

#pragma unroll 2
  for (int i = tid * 4; i < VPB; i += TPB * 4) {
    float4 V = *(const float4*)(cb + i);
    const float* vp = (const float*)&V;
#pragma unroll
    for (int j = 0; j < 4; ++j) {
      uint32_t bits = __float_as_uint(vp[j]);
      uint32_t t12 = bits >> L1SH;
      if (t12 > b1) local += vp[j];
      else if (t12 == b1) atomicAdd(&sh[(bits >> 7) & (NBIN - 1)], 1u);
    }
  }

  local = wred64(local);
  if ((tid & 63) == 0) wsum[tid >> 6] = local;
  __syncthreads();
  if (tid == 0) {
    float t = 0.f;
#pragma unroll
    for (int w = 0; w < TPB / 64; ++w) t += wsum[w];
    if (t != 0.f) atomicAdd(&sum_above[b * NCOPY + (blk & (NCOPY - 1))], t);
  }
  for (int i = tid; i < NBIN; i += TPB) {
    uint32_t cv = sh[i];
    if (cv) atomicAdd(&hist2[(size_t)b * NBIN + i], cv);
  }
}

// Scan a histogram from the top to find the bucket containing the k-th
// largest element. One block per batch.
__global__ __launch_bounds__(256) void k_scan1(
    const uint32_t* __restrict__ hist,
    uint32_t* __restrict__ out_b, uint32_t* __restrict__ out_rem)
{
  const int b = blockIdx.x;
  const int tid = threadIdx.x;
  __shared__ uint32_t chunk[256];
  const int per = NBIN >> 8;
  const uint32_t* h = hist + (size_t)b * NBIN;
  uint32_t s = 0;
  for (int j = 0; j < per; ++j) s += h[tid * per + j];
  chunk[tid] = s;
  __syncthreads();
  if (tid == 0) {
    uint32_t k = KSEL, cum = 0;
    int ci = 255;
    for (; ci > 0; --ci) {
      uint32_t c = chunk[ci];
      if (cum + c >= k) break;
      cum += c;
    }
    int bkt = ci * per;
    for (int j = per - 1; j >= 0; --j) {
      uint32_t c = h[ci * per + j];
      if (cum + c >= k) { bkt = ci * per + j; break; }
      cum += c;
    }
    out_b[b] = (uint32_t)bkt;
    out_rem[b] = k - cum;   // 1 <= rem <= hist[bkt]
  }
}

// Final: scan hist2 for both batches; reconstruct the missing "within L1
// bucket, above the L2 tie bucket" sum from hist2 counts x midpoint values
// (top 24 bits of each element are pinned by its bucket; error <= 64 ulp/elem);
// combine with sum_above, tie remainder, and dice partials -> scalar loss.
__global__ __launch_bounds__(256) void k_final(
    const uint32_t* __restrict__ hist2, const uint32_t* __restrict__ b1p,
    const uint32_t* __restrict__ rem1, const float* __restrict__ sum_above,
    const float* __restrict__ dice_acc, float* __restrict__ out)
{
  const int tid = threadIdx.x;
  __shared__ uint32_t chunk[256];
  __shared__ uint32_t sbkt, srem;
  __shared__ float wpart[4];
  __shared__ float ts[NB];
  __shared__ float comp[24];
  const int per = NBIN >> 8;   // 16

  for (int b = 0; b < NB; ++b) {
    const uint32_t* h = hist2 + (size_t)b * NBIN;
    uint32_t s = 0;
    for (int j = 0; j < per; ++j) s += h[tid * per + j];
    chunk[tid] = s;
    __syncthreads();
    if (tid == 0) {
      uint32_t k = rem1[b], cum = 0;
      int ci = 255;
      for (; ci > 0; --ci) {
        uint32_t c = chunk[ci];
        if (cum + c >= k) break;
        cum += c;
      }
      int bkt = ci * per;
      for (int j = per - 1; j >= 0; --j) {
        uint32_t c = h[ci * per + j];
        if (cum + c >= k) { bkt = ci * per + j; break; }
        cum += c;
      }
      sbkt = (uint32_t)bkt;
      srem = k - cum;          // 1 <= srem <= h[bkt]
    }
    __syncthreads();
    const uint32_t b1 = b1p[b];
    const int bkt = (int)sbkt;
    // Weighted sum of counts in L2 buckets strictly above the tie bucket.
    float w = 0.f;
    for (int i = tid; i < NBIN; i += 256) {
      if (i > bkt) {
        uint32_t c = h[i];
        if (c) {
          uint32_t bits = (b1 << L1SH) | ((uint32_t)i << 7) | 64u;
          w += (float)c * __uint_as_float(bits);
        }
      }
    }
    w = wred64(w);
    if ((tid & 63) == 0) wpart[tid >> 6] = w;
    __syncthreads();
    if (tid == 0) {
      float sa = 0.f;
      for (int r = 0; r < NCOPY; ++r) sa += sum_above[b * NCOPY + r];
      uint32_t bits = (b1 << L1SH) | ((uint32_t)bkt << 7) | 64u;
      ts[b] = sa + wpart[0] + wpart[1] + wpart[2] + wpart[3]
              + (float)srem * __uint_as_float(bits);
    }
    __syncthreads();
  }

  // dice: reduce the 64 spread copies of 24 components
  if (tid < 24) {
    float a = 0.f;
    for (int r = 0; r < NCOPY; ++r) a += dice_acc[(size_t)r * 24 + tid];
    comp[tid] = a;
  }
  __syncthreads();
  if (tid == 0) {
    float dl = 0.f;
#pragma unroll
    for (int b = 0; b < 2; ++b)
#pragma unroll
      for (int c = 1; c < 4; ++c) {
        float sp = comp[b * 12 + c];
        float nm = comp[b * 12 + 4 + c];
        float ct = comp[b * 12 + 8 + c];
        dl += 1.f - (2.f * nm) / (sp + ct + 1e-6f);
      }
    float topk = 0.5f * (ts[0] + ts[1]) / (float)KSEL;
    out[0] = topk + 0.5f * (dl / 6.f);
  }
}

extern "C" void kernel_launch(void* const* d_in, const int* in_sizes, int n_in,
                              void* d_out, int out_size, void* d_ws, size_t ws_size,
                              hipStream_t stream) {
  (void)in_sizes; (void)n_in; (void)out_size; (void)ws_size;
  const float* logits = (const float*)d_in[0];
  const float* target = (const float*)d_in[1];
  float* out = (float*)d_out;

  // Workspace layout: [ce: NB*NVOX floats][hist/scan/dice accumulators]
  char* ws = (char*)d_ws;
  float* ce = (float*)ws;
  const size_t CE_BYTES = (size_t)NB * NVOX * sizeof(float);   // 16 MiB
  uint32_t* small = (uint32_t*)(ws + CE_BYTES);
  uint32_t* hist1 = small;                 // NB*NBIN
  uint32_t* hist2 = hist1 + NB * NBIN;     // NB*NBIN
  uint32_t* b1   = hist2 + NB * NBIN;
  uint32_t* rem1 = b1 + NB;
  float* sum_above = (float*)(rem1 + NB);  // NB*NCOPY
  float* dice_acc  = sum_above + NB * NCOPY; // NCOPY*NB*12
  const size_t SMALL_BYTES =
      (size_t)((char*)(dice_acc + (size_t)NCOPY * NB * 12) - (char*)small);

  // ws is re-poisoned to 0xAA before every launch: zero all accumulators.
  hipMemsetAsync(small, 0, SMALL_BYTES, stream);

  k1_ce_dice_hist<<<NBLK, TPB, 0, stream>>>(logits, target, ce, hist1, dice_acc);
  k_scan1<<<NB, 256, 0, stream>>>(hist1, b1, rem1);
  k_pass2<<<NBLK, TPB, 0, stream>>>(ce, b1, hist2, sum_above);
  k_final<<<1, 256, 0, stream>>>(hist2, b1, rem1, sum_above, dice_acc, out);
}